// Round 1
// baseline (1601.945 us; speedup 1.0000x reference)
//
#include <hip/hip_runtime.h>
#include <hip/hip_bf16.h>
#include <stdint.h>

#define N_TOKEN 16384
#define N_EMBED 512
#define QBLK 64
#define KVB 32
#define NKV_TILES (N_TOKEN / KVB)

typedef __attribute__((ext_vector_type(8))) short bf16x8;
typedef __attribute__((ext_vector_type(4))) float f32x4;

__device__ __forceinline__ unsigned short f2bf(float f) {
  unsigned u = __float_as_uint(f);
  u = (u + 0x7FFFu + ((u >> 16) & 1u)) >> 16;
  return (unsigned short)u;
}
__device__ __forceinline__ float bf2f(unsigned short h) {
  return __uint_as_float(((unsigned)h) << 16);
}

__device__ __forceinline__ void load_lds16(const void* g, void* l) {
  __builtin_amdgcn_global_load_lds((const __attribute__((address_space(1))) void*)g,
                                   (__attribute__((address_space(3))) void*)l, 16, 0, 0);
}

// ---------------- prep: f32 -> bf16 (8 elems/thread) ----------------
__global__ void cvt_bf16_kernel(const float* __restrict__ in, unsigned short* __restrict__ out, int n8) {
  int i = blockIdx.x * blockDim.x + threadIdx.x;
  if (i >= n8) return;
  float4 a = ((const float4*)in)[i * 2 + 0];
  float4 b = ((const float4*)in)[i * 2 + 1];
  uint4 o;
  o.x = (unsigned)f2bf(a.x) | ((unsigned)f2bf(a.y) << 16);
  o.y = (unsigned)f2bf(a.z) | ((unsigned)f2bf(a.w) << 16);
  o.z = (unsigned)f2bf(b.x) | ((unsigned)f2bf(b.y) << 16);
  o.w = (unsigned)f2bf(b.z) | ((unsigned)f2bf(b.w) << 16);
  ((uint4*)out)[i] = o;
}

// ---------------- prep: value_w [N][E] f32 -> vt [E][N] bf16 ----------------
__global__ void transpose_cvt_kernel(const float* __restrict__ in, unsigned short* __restrict__ out) {
  __shared__ float tile[64][65];
  int n0 = blockIdx.x * 64;
  int e0 = blockIdx.y * 64;
  int c = threadIdx.x & 63;
  int r0 = threadIdx.x >> 6;
#pragma unroll
  for (int r = r0; r < 64; r += 4)
    tile[r][c] = in[(size_t)(n0 + r) * N_EMBED + e0 + c];
  __syncthreads();
#pragma unroll
  for (int r = r0; r < 64; r += 4)
    out[(size_t)(e0 + r) * N_TOKEN + n0 + c] = f2bf(tile[c][r]);
}

// ---------------- main fused flash kernel ----------------
// 256 blocks x 256 threads. Block = 64 q-rows. Wave w: E-slice / D-slice [128w,128w+128).
__global__ __launch_bounds__(256, 1) void flash_kernel(
    const unsigned short* __restrict__ xb,   // [T][512] bf16
    const unsigned short* __restrict__ kb,   // [N][512] bf16 (lin_w)
    const unsigned short* __restrict__ vt,   // [512][N] bf16 (value_w^T)
    const float* __restrict__ bias,          // [N]
    const float* __restrict__ xf,            // [T][512] f32 (residual)
    float* __restrict__ out)                 // [T][512] f32
{
  __shared__ __align__(16) unsigned char lds[144 * 1024];
  unsigned char* Ks = lds;               // 2 x 32KB : K tile [32][512] bf16, row-swizzled
  unsigned char* Vs = lds + 64 * 1024;   // 2 x 32KB : V^T tile [512][32] bf16, row-swizzled
  unsigned char* Sp = lds + 128 * 1024;  // 16KB : partial S [4][64][32] bf16; Sp[0] doubles as P

  const int tid = threadIdx.x;
  const int w = tid >> 6;
  const int lane = tid & 63;
  const int g = lane >> 4;
  const int l15 = lane & 15;
  const int qbase = blockIdx.x * QBLK;

  // Q fragments in registers: rows qbase+16rf+l15, E-slice [w*128, +128)
  bf16x8 q[4][4];
#pragma unroll
  for (int rf = 0; rf < 4; ++rf)
#pragma unroll
    for (int kk = 0; kk < 4; ++kk)
      q[rf][kk] = *(const bf16x8*)(xb + (size_t)(qbase + 16 * rf + l15) * N_EMBED + w * 128 + kk * 32 + g * 8);

  const f32x4 fzero = {0.f, 0.f, 0.f, 0.f};
  f32x4 acc[4][8];
#pragma unroll
  for (int rf = 0; rf < 4; ++rf)
#pragma unroll
    for (int cf = 0; cf < 8; ++cf) acc[rf][cf] = fzero;
  float lsum[4] = {0.f, 0.f, 0.f, 0.f};

  auto stage = [&](int half, int t) {
    const unsigned char* kg = (const unsigned char*)(kb + (size_t)t * KVB * N_EMBED);
    unsigned char* Kd = Ks + half * (32 * 1024);
#pragma unroll
    for (int it = 0; it < 8; ++it) {
      int c = tid + 256 * it;          // 2048 chunks of 16B
      int row = c >> 6;                // 64 chunks per 1024B row
      int cb = (c & 63) * 16;
      load_lds16(kg + row * 1024 + (cb ^ ((row & 7) << 4)), Kd + c * 16);
    }
    unsigned char* Vd = Vs + half * (32 * 1024);
#pragma unroll
    for (int it = 0; it < 8; ++it) {
      int c = tid + 256 * it;          // 2048 chunks; 4 per 64B e-row
      int e = c >> 2;
      int kvb = (c & 3) * 16;
      load_lds16((const unsigned char*)vt + (size_t)e * (N_TOKEN * 2) + (size_t)t * (KVB * 2) +
                     (kvb ^ (((e >> 1) & 3) << 4)),
                 Vd + c * 16);
    }
  };

  stage(0, 0);

  for (int kt = 0; kt < NKV_TILES; ++kt) {
    const int buf = kt & 1;
    const unsigned char* Kb = Ks + buf * (32 * 1024);
    const unsigned char* Vb = Vs + buf * (32 * 1024);

    asm volatile("s_waitcnt vmcnt(0)" ::: "memory");
    __syncthreads();
    if (kt + 1 < NKV_TILES) stage(buf ^ 1, kt + 1);

    // ---- QK^T partial over this wave's E-slice
    f32x4 s[4][2];
#pragma unroll
    for (int rf = 0; rf < 4; ++rf) { s[rf][0] = fzero; s[rf][1] = fzero; }
#pragma unroll
    for (int kk = 0; kk < 4; ++kk) {
      bf16x8 bk[2];
#pragma unroll
      for (int nf = 0; nf < 2; ++nf) {
        int row = 16 * nf + l15;
        int cb = w * 256 + kk * 64 + g * 16;
        bk[nf] = *(const bf16x8*)(Kb + row * 1024 + (cb ^ ((row & 7) << 4)));
      }
#pragma unroll
      for (int rf = 0; rf < 4; ++rf) {
        s[rf][0] = __builtin_amdgcn_mfma_f32_16x16x32_bf16(q[rf][kk], bk[0], s[rf][0], 0, 0, 0);
        s[rf][1] = __builtin_amdgcn_mfma_f32_16x16x32_bf16(q[rf][kk], bk[1], s[rf][1], 0, 0, 0);
      }
    }
    // ---- write bf16 partial [w][64][32], row-swizzled
#pragma unroll
    for (int rf = 0; rf < 4; ++rf)
#pragma unroll
      for (int nf = 0; nf < 2; ++nf)
#pragma unroll
        for (int j = 0; j < 4; ++j) {
          int row = 16 * rf + 4 * g + j;
          int kvb = (16 * nf + l15) * 2;
          *(unsigned short*)(Sp + w * 4096 + row * 64 + (kvb ^ (((row >> 1) & 3) << 4))) =
              f2bf(s[rf][nf][j]);
        }
    __syncthreads();

    // ---- wave w reduces rows [16w,16w+16): sum partials + bias, exp, write P (= Sp[0])
    {
      int row = 16 * w + l15;
      int off = row * 64 + ((g * 16) ^ (((row >> 1) & 3) << 4));
      float sm[8] = {0, 0, 0, 0, 0, 0, 0, 0};
#pragma unroll
      for (int pp = 0; pp < 4; ++pp) {
        bf16x8 v = *(const bf16x8*)(Sp + pp * 4096 + off);
#pragma unroll
        for (int k = 0; k < 8; ++k) sm[k] += bf2f((unsigned short)v[k]);
      }
      const float* bp = bias + kt * KVB + g * 8;
      float4 b0 = *(const float4*)bp;
      float4 b1 = *(const float4*)(bp + 4);
      float bb[8] = {b0.x, b0.y, b0.z, b0.w, b1.x, b1.y, b1.z, b1.w};
      bf16x8 pb;
#pragma unroll
      for (int k = 0; k < 8; ++k) {
        float p = exp2f((sm[k] + bb[k]) * 1.44269504f);
        pb[k] = (short)f2bf(p);
      }
      *(bf16x8*)(Sp + off) = pb;  // P row-quarter (aliases own partial rows, read-before-write in-wave)
    }
    __syncthreads();

    // ---- gather P A-fragments (all quarters), accumulate row sums
    bf16x8 pa[4];
#pragma unroll
    for (int rf = 0; rf < 4; ++rf) {
      int row = 16 * rf + l15;
      pa[rf] = *(const bf16x8*)(Sp + row * 64 + ((g * 16) ^ (((row >> 1) & 3) << 4)));
      float rs = 0.f;
#pragma unroll
      for (int k = 0; k < 8; ++k) rs += bf2f((unsigned short)pa[rf][k]);
      rs += __shfl_xor(rs, 16, 64);
      rs += __shfl_xor(rs, 32, 64);
      lsum[rf] += rs;
    }
    // ---- PV: O[64 x 128w..] += P * V
#pragma unroll
    for (int cf = 0; cf < 8; ++cf) {
      int e = 128 * w + 16 * cf + l15;
      bf16x8 bv = *(const bf16x8*)(Vb + e * 64 + ((g * 16) ^ (((e >> 1) & 3) << 4)));
#pragma unroll
      for (int rf = 0; rf < 4; ++rf)
        acc[rf][cf] = __builtin_amdgcn_mfma_f32_16x16x32_bf16(pa[rf], bv, acc[rf][cf], 0, 0, 0);
    }
  }

  // ---- epilogue: out = acc/l + x
  float invl[4];
#pragma unroll
  for (int rf = 0; rf < 4; ++rf) invl[rf] = 1.0f / lsum[rf];
#pragma unroll
  for (int rf = 0; rf < 4; ++rf)
#pragma unroll
    for (int j = 0; j < 4; ++j) {
      float il = __shfl(invl[rf], 4 * g + j, 64);  // lsum lives at lane=row&15; needed at row=4g+j
      int row = qbase + 16 * rf + 4 * g + j;
#pragma unroll
      for (int cf = 0; cf < 8; ++cf) {
        int col = 128 * w + 16 * cf + l15;
        size_t idx = (size_t)row * N_EMBED + col;
        out[idx] = acc[rf][cf][j] * il + xf[idx];
      }
    }
}

extern "C" void kernel_launch(void* const* d_in, const int* in_sizes, int n_in,
                              void* d_out, int out_size, void* d_ws, size_t ws_size,
                              hipStream_t stream) {
  const float* x = (const float*)d_in[0];       // [8,2048,512] f32
  const float* lin_w = (const float*)d_in[1];   // [16384,512] f32
  const float* lin_b = (const float*)d_in[2];   // [16384] f32
  const float* value_w = (const float*)d_in[3]; // [16384,512] f32
  float* outp = (float*)d_out;

  unsigned short* xb = (unsigned short*)d_ws;                         // 16MB
  unsigned short* wb = (unsigned short*)((char*)d_ws + (16 << 20));   // 16MB
  unsigned short* vt = (unsigned short*)((char*)d_ws + (32 << 20));   // 16MB

  const int n8 = (N_TOKEN * N_EMBED) / 8;  // 1048576
  cvt_bf16_kernel<<<n8 / 256, 256, 0, stream>>>(x, xb, n8);
  cvt_bf16_kernel<<<n8 / 256, 256, 0, stream>>>(lin_w, wb, n8);
  transpose_cvt_kernel<<<dim3(N_TOKEN / 64, N_EMBED / 64), 256, 0, stream>>>(value_w, vt);
  flash_kernel<<<N_TOKEN / QBLK, 256, 0, stream>>>(xb, wb, vt, lin_b, x, outp);
}